// Round 1
// baseline (270.568 us; speedup 1.0000x reference)
//
#include <hip/hip_runtime.h>

#define EMBD 32
#define KN 10

// Two-phase SAGE layer.
// Phase 1 (gather, lane-per-dim): each half-wave (32 lanes) reads feature rows
//   coalesced (128 B per half-wave) and stages the 64-float combined vector
//   [self, mean(neigh)] into LDS transposed: sh[j][t], t = thread-in-block.
//   Padding 257 makes bank = (j+t)%32 -> conflict-free writes AND reads.
// Phase 2 (compute, thread-per-node): thread t pulls comb[64] into registers
//   (64 ds_read_b32 per wave serve 64 nodes), then out[e] = relu(comb . W[e,:]).
//   W accesses are wave-uniform -> scalar loads (s_load), FMAs use SGPR operand.
template<bool REMAP>
__global__ __launch_bounds__(256, 2)
void sage_layer(const float* __restrict__ feat,   // [n_nodes, 32] feature table
                const float* __restrict__ W,      // [32][64] row-major
                const int*   __restrict__ neigh,  // [N_NODES, 10]
                const int*   __restrict__ remap,  // row -> node id (REMAP only)
                float*       __restrict__ out,    // [n_rows, 32]
                int n_rows)
{
    __shared__ float sh[64][257];
    const int tid  = threadIdx.x;
    const int wid  = tid >> 6;        // wave id 0..3
    const int lane = tid & 63;
    const int half = lane >> 5;       // which node of the pair
    const int j    = lane & 31;       // feature dim this lane covers
    const int row0 = blockIdx.x << 8;

    // ---- gather phase: wave w stages columns t in [64w, 64w+64)
    #pragma unroll 4
    for (int i = 0; i < 32; ++i) {
        int t = (wid << 6) + (i << 1) + half;
        int r = row0 + t;
        if (r >= n_rows) r = n_rows - 1;          // clamp; store is guarded later
        const int node = REMAP ? remap[r] : r;
        const float self = feat[node * EMBD + j]; // coalesced 128 B per half-wave
        const int* nb = neigh + node * KN;
        float agg = 0.f;
        #pragma unroll
        for (int k = 0; k < KN; ++k) {
            int idx = nb[k];                      // uniform per half-wave (L1 broadcast)
            agg += feat[idx * EMBD + j];          // coalesced 128 B per half-wave
        }
        sh[j][t]      = self;                     // bank (j+t)%32: conflict-free
        sh[32 + j][t] = agg * 0.1f;
    }
    __syncthreads();

    // ---- compute phase: thread t owns output row row0+t
    float comb[64];
    #pragma unroll
    for (int jj = 0; jj < 64; ++jj)
        comb[jj] = sh[jj][tid];                   // 1 ds_read_b32 per jj serves all 64 lanes

    const int  r     = row0 + tid;
    const bool valid = (r < n_rows);
    float* orow = out + (size_t)r * EMBD;

    for (int e4 = 0; e4 < 8; ++e4) {
        float oq[4];
        #pragma unroll
        for (int q = 0; q < 4; ++q) {
            const float* wr = W + (e4 * 4 + q) * 64;   // wave-uniform -> s_load
            float acc = 0.f;
            #pragma unroll
            for (int jj = 0; jj < 64; ++jj)
                acc = fmaf(comb[jj], wr[jj], acc);
            oq[q] = acc > 0.f ? acc : 0.f;             // relu
        }
        if (valid)
            *(float4*)(orow + e4 * 4) = make_float4(oq[0], oq[1], oq[2], oq[3]);
    }
}

extern "C" void kernel_launch(void* const* d_in, const int* in_sizes, int n_in,
                              void* d_out, int out_size, void* d_ws, size_t ws_size,
                              hipStream_t stream)
{
    // setup_inputs() dict order: emb, W1, W2, node_batch, neigh  (all f32 / int32)
    const float* emb        = (const float*)d_in[0];
    const float* W1         = (const float*)d_in[1];
    const float* W2         = (const float*)d_in[2];
    const int*   node_batch = (const int*)  d_in[3];
    const int*   neigh      = (const int*)  d_in[4];

    const int N = in_sizes[0] / EMBD;   // 500000
    const int B = in_sizes[3];          // 100000

    float* h1 = (float*)d_ws;           // N*32 floats = 64 MB scratch

    // Layer 1: h1 for every node (identity row->node mapping)
    sage_layer<false><<<(N + 255) / 256, 256, 0, stream>>>(
        emb, W1, neigh, nullptr, h1, N);

    // Layer 2: batch rows, node = node_batch[row], features from h1
    sage_layer<true><<<(B + 255) / 256, 256, 0, stream>>>(
        h1, W2, neigh, node_batch, (float*)d_out, B);
}

// Round 2
// 236.481 us; speedup vs baseline: 1.1441x; 1.1441x over previous
//
#include <hip/hip_runtime.h>

#define EMBD 32
#define KN 10

__device__ __forceinline__ float bf2f(unsigned short u) {
    union { unsigned int u; float f; } c; c.u = ((unsigned int)u) << 16; return c.f;
}
__device__ __forceinline__ unsigned short f2bf(float f) {
    union { float f; unsigned int u; } c; c.f = f;
    unsigned int u = c.u + 0x7FFFu + ((c.u >> 16) & 1u);   // RNE
    return (unsigned short)(u >> 16);
}

// f32 -> bf16 table conversion (streaming, ~96 MB traffic)
__global__ __launch_bounds__(256)
void cvt_bf16_kernel(const float4* __restrict__ in, ushort4* __restrict__ out, int n4)
{
    int i = blockIdx.x * 256 + threadIdx.x;
    if (i < n4) {
        float4 v = in[i];
        ushort4 o;
        o.x = f2bf(v.x); o.y = f2bf(v.y); o.z = f2bf(v.z); o.w = f2bf(v.w);
        out[i] = o;
    }
}

// One SAGE layer, 64 rows per 256-thread block.
// Gather: 8 half-waves x 8 rows each; feature rows are bf16 (64 B = 1 line per
//   half-wave, coalesced). Staged feature-major sh[feat][row] (+1 pad:
//   write banks (j+rl)%32 distinct, read stride-1 = 2-way free).
// Compute: wave w computes outputs e in [8w, 8w+8) for all 64 rows; comb is
//   STREAMED from LDS (1 ds_read_b32 shared by 8 FMAs) -> ~64 VGPRs, no
//   comb[64] register array. W base made wave-uniform via readfirstlane so
//   all W traffic is s_load from K$.
template<bool REMAP, bool OUT_BF16>
__global__ __launch_bounds__(256, 4)
void sage_layer(const unsigned short* __restrict__ feat, // [n_nodes, 32] bf16
                const float* __restrict__ W,             // [32][64] f32
                const int*   __restrict__ neigh,         // [N_NODES, 10]
                const int*   __restrict__ remap,         // row -> node (REMAP)
                void*        __restrict__ out,           // [n_rows, 32]
                int n_rows)
{
    __shared__ float sh[64][65];          // [feature][row]
    const int tid  = threadIdx.x;
    const int row0 = blockIdx.x << 6;

    // ---- gather phase ----
    {
        const int hw = tid >> 5;          // half-wave 0..7
        const int j  = tid & 31;          // feature dim
        #pragma unroll 2
        for (int i = 0; i < 8; ++i) {
            const int rl = hw * 8 + i;    // local row
            int r = row0 + rl;
            if (r >= n_rows) r = n_rows - 1;        // clamp; store guarded later
            const int node = REMAP ? remap[r] : r;
            const float self = bf2f(feat[node * EMBD + j]);   // 64 B coalesced
            const int* nb = neigh + node * KN;
            float agg = 0.f;
            #pragma unroll
            for (int k = 0; k < KN; ++k)
                agg += bf2f(feat[nb[k] * EMBD + j]);          // 64 B coalesced
            sh[j][rl]      = self;
            sh[32 + j][rl] = agg * 0.1f;
        }
    }
    __syncthreads();

    // ---- compute phase: wave wid -> outputs [8*wid, 8*wid+8) ----
    const int row = tid & 63;
    const int wid = __builtin_amdgcn_readfirstlane(tid >> 6);
    const float* Wb = W + wid * 8 * 64;   // wave-uniform -> scalar loads

    float acc[8] = {0.f,0.f,0.f,0.f,0.f,0.f,0.f,0.f};
    #pragma unroll 8
    for (int jj = 0; jj < 64; ++jj) {
        const float c = sh[jj][row];      // stride-1 across lanes: conflict-free
        #pragma unroll
        for (int q = 0; q < 8; ++q)
            acc[q] = fmaf(c, Wb[q * 64 + jj], acc[q]);
    }

    const int r = row0 + row;
    if (r < n_rows) {
        if (OUT_BF16) {
            unsigned int pk[4];
            #pragma unroll
            for (int q = 0; q < 4; ++q) {
                float a0 = fmaxf(acc[2*q],     0.f);
                float a1 = fmaxf(acc[2*q + 1], 0.f);
                pk[q] = (unsigned int)f2bf(a0) | ((unsigned int)f2bf(a1) << 16);
            }
            uint4* dst = (uint4*)((unsigned short*)out + (size_t)r * EMBD + wid * 8);
            *dst = make_uint4(pk[0], pk[1], pk[2], pk[3]);
        } else {
            float* dst = (float*)out + (size_t)r * EMBD + wid * 8;
            ((float4*)dst)[0] = make_float4(fmaxf(acc[0],0.f), fmaxf(acc[1],0.f),
                                            fmaxf(acc[2],0.f), fmaxf(acc[3],0.f));
            ((float4*)dst)[1] = make_float4(fmaxf(acc[4],0.f), fmaxf(acc[5],0.f),
                                            fmaxf(acc[6],0.f), fmaxf(acc[7],0.f));
        }
    }
}

extern "C" void kernel_launch(void* const* d_in, const int* in_sizes, int n_in,
                              void* d_out, int out_size, void* d_ws, size_t ws_size,
                              hipStream_t stream)
{
    // dict order: emb [N,32] f32, W1 [32,64] f32, W2 [32,64] f32,
    //             node_batch [B] i32, neigh [N,10] i32
    const float* emb        = (const float*)d_in[0];
    const float* W1         = (const float*)d_in[1];
    const float* W2         = (const float*)d_in[2];
    const int*   node_batch = (const int*)  d_in[3];
    const int*   neigh      = (const int*)  d_in[4];

    const int N = in_sizes[0] / EMBD;   // 500000
    const int B = in_sizes[3];          // 100000

    unsigned short* emb_bf = (unsigned short*)d_ws;              // 32 MB
    unsigned short* h1_bf  = emb_bf + (size_t)N * EMBD;          // 32 MB

    // 1) emb f32 -> bf16
    const int n4 = (N * EMBD) / 4;
    cvt_bf16_kernel<<<(n4 + 255) / 256, 256, 0, stream>>>(
        (const float4*)emb, (ushort4*)emb_bf, n4);

    // 2) layer 1: all N nodes, h1 stored bf16
    sage_layer<false, true><<<(N + 63) / 64, 256, 0, stream>>>(
        emb_bf, W1, neigh, nullptr, (void*)h1_bf, N);

    // 3) layer 2: batch rows, f32 output
    sage_layer<true, false><<<(B + 63) / 64, 256, 0, stream>>>(
        h1_bf, W2, neigh, node_batch, d_out, B);
}